// Round 2
// baseline (3319.284 us; speedup 1.0000x reference)
//
#include <hip/hip_runtime.h>

typedef _Float16 h2 __attribute__((ext_vector_type(2)));
typedef _Float16 h8 __attribute__((ext_vector_type(8)));
typedef float f4 __attribute__((ext_vector_type(4)));

static constexpr int NB = 128;   // batch
static constexpr int NT = 4096;  // time
static constexpr int NI = 64;    // input
static constexpr int NH = 256;   // hidden
static constexpr int NO = 64;    // output
static constexpr int CHUNK = 16; // timesteps of x staged per LDS chunk

__device__ __forceinline__ h2 cvt2(float a, float b) {
    h2 r;
    r[0] = (_Float16)a;
    r[1] = (_Float16)b;
    return r;
}

__device__ __forceinline__ float fdot2(h2 a, h2 b, float c) {
#if __has_builtin(__builtin_amdgcn_fdot2)
    return __builtin_amdgcn_fdot2(a, b, c, false);
#else
    return c + (float)a[0] * (float)b[0] + (float)a[1] * (float)b[1];
#endif
}

__device__ __forceinline__ float fast_tanh(float x) {
    // tanh(x) = 1 - 2/(e^{2x}+1); exp2-based, saturates correctly at +-inf
#if __has_builtin(__builtin_amdgcn_exp2f)
    float e = __builtin_amdgcn_exp2f(x * 2.885390081777927f); // 2*log2(e)
#else
    float e = exp2f(x * 2.885390081777927f);
#endif
#if __has_builtin(__builtin_amdgcn_rcpf)
    return 1.0f - 2.0f * __builtin_amdgcn_rcpf(e + 1.0f);
#else
    return 1.0f - 2.0f / (e + 1.0f);
#endif
}

__global__ __launch_bounds__(256, 1) void rnn_persist(
    const float* __restrict__ x,    // [B,T,I]
    const float* __restrict__ wih,  // [H,I]
    const float* __restrict__ whhg, // [H,H]
    const float* __restrict__ bih,  // [H]
    const float* __restrict__ bhh,  // [H]
    const float* __restrict__ wy,   // [O,H]
    const float* __restrict__ by,   // [O]
    float* __restrict__ out)        // [B,O]
{
    __shared__ __align__(16) h2 hbuf[2][NH / 2];          // 2 x 256 B
    __shared__ __align__(16) h2 xbuf[2][CHUNK * NI / 2];  // 2 x 1 KB
    __shared__ float hf[NH];

    const int j = threadIdx.x;  // hidden unit owned by this thread
    const int b = blockIdx.x;   // batch element owned by this block

    // ---- load weights into registers as fp16 pairs ----
    h2 whh[NH / 2];  // 128 VGPRs: row j of W_hh
    {
        const f4* src = (const f4*)(whhg + (size_t)j * NH);
#pragma unroll
        for (int q = 0; q < NH / 4; ++q) {
            f4 v = src[q];
            whh[2 * q]     = cvt2(v.x, v.y);
            whh[2 * q + 1] = cvt2(v.z, v.w);
        }
    }
    h2 wi[NI / 2];  // 32 VGPRs: row j of W_ih
    {
        const f4* src = (const f4*)(wih + (size_t)j * NI);
#pragma unroll
        for (int q = 0; q < NI / 4; ++q) {
            f4 v = src[q];
            wi[2 * q]     = cvt2(v.x, v.y);
            wi[2 * q + 1] = cvt2(v.z, v.w);
        }
    }
    const float bias = bih[j] + bhh[j];

    const float* xb = x + (size_t)b * NT * NI;

    // ---- stage x chunk 0 (16 steps * 64 floats = 1024 floats; 4/thread) ----
    {
        f4 v = ((const f4*)xb)[j];
        xbuf[0][2 * j]     = cvt2(v.x, v.y);
        xbuf[0][2 * j + 1] = cvt2(v.z, v.w);
    }
    // ---- zero h(0) ----
    if (j < NH / 2) {
        h2 z;
        z[0] = (_Float16)0.f;
        z[1] = (_Float16)0.f;
        hbuf[0][j] = z;
    }
    __syncthreads();

    float hval = 0.f;
    f4 xnext;
    int p = 0;  // h read-buffer parity

    for (int t = 0; t < NT; ++t) {
        const int s = t & (CHUNK - 1);
        const int c = t >> 4;

        // issue next-chunk global load early (16-step prefetch distance)
        if (s == 0 && t + CHUNK < NT) {
            xnext = ((const f4*)(xb + (size_t)(t + CHUNK) * NI))[j];
        }

        float a0 = bias, a1 = 0.f, a2 = 0.f, a3 = 0.f;

        // ---- input projection: 64 fp16 values, 8 x ds_read_b128 ----
        {
            const h8* xp = (const h8*)(&xbuf[c & 1][s * (NI / 2)]);
#pragma unroll
            for (int r = 0; r < NI / 8; ++r) {
                h8 v = xp[r];
                a0 = fdot2(__builtin_shufflevector(v, v, 0, 1), wi[4 * r + 0], a0);
                a1 = fdot2(__builtin_shufflevector(v, v, 2, 3), wi[4 * r + 1], a1);
                a2 = fdot2(__builtin_shufflevector(v, v, 4, 5), wi[4 * r + 2], a2);
                a3 = fdot2(__builtin_shufflevector(v, v, 6, 7), wi[4 * r + 3], a3);
            }
        }
        // ---- recurrent matvec: 256 fp16 values, 32 x ds_read_b128 ----
        {
            const h8* hp = (const h8*)(&hbuf[p][0]);
#pragma unroll
            for (int r = 0; r < NH / 8; ++r) {
                h8 v = hp[r];
                a0 = fdot2(__builtin_shufflevector(v, v, 0, 1), whh[4 * r + 0], a0);
                a1 = fdot2(__builtin_shufflevector(v, v, 2, 3), whh[4 * r + 1], a1);
                a2 = fdot2(__builtin_shufflevector(v, v, 4, 5), whh[4 * r + 2], a2);
                a3 = fdot2(__builtin_shufflevector(v, v, 6, 7), whh[4 * r + 3], a3);
            }
        }
        const float pre = (a0 + a1) + (a2 + a3);
        hval = fast_tanh(pre);

        // write my h into the other buffer (one fp16)
        ((_Float16*)(&hbuf[p ^ 1][0]))[j] = (_Float16)hval;

        // at chunk end, commit the prefetched x chunk to its LDS buffer
        if (s == CHUNK - 1 && t + 1 < NT) {
            xbuf[(c + 1) & 1][2 * j]     = cvt2(xnext.x, xnext.y);
            xbuf[(c + 1) & 1][2 * j + 1] = cvt2(xnext.z, xnext.w);
        }

        __syncthreads();
        p ^= 1;
    }

    // ---- epilogue: y = h_last @ W_y^T + b_y ----
    hf[j] = hval;
    __syncthreads();
    if (j < NO) {
        float acc = by[j];
        const f4* wrow = (const f4*)(wy + (size_t)j * NH);
        const f4* hp = (const f4*)hf;
#pragma unroll
        for (int q = 0; q < NH / 4; ++q) {
            f4 w = wrow[q];
            f4 h = hp[q];
            acc += w.x * h.x + w.y * h.y + w.z * h.z + w.w * h.w;
        }
        out[b * NO + j] = acc;
    }
}

extern "C" void kernel_launch(void* const* d_in, const int* in_sizes, int n_in,
                              void* d_out, int out_size, void* d_ws, size_t ws_size,
                              hipStream_t stream) {
    const float* x   = (const float*)d_in[0];
    const float* wih = (const float*)d_in[1];
    const float* whh = (const float*)d_in[2];
    const float* bih = (const float*)d_in[3];
    const float* bhh = (const float*)d_in[4];
    const float* wy  = (const float*)d_in[5];
    const float* by  = (const float*)d_in[6];
    float* out = (float*)d_out;

    rnn_persist<<<dim3(NB), dim3(256), 0, stream>>>(x, wih, whh, bih, bhh, wy, by, out);
}